// Round 8
// baseline (141.672 us; speedup 1.0000x reference)
//
#include <hip/hip_runtime.h>
#include <hip/hip_bf16.h>

#define NDIM 16
#define HDIM 128
#define BATCH 256
#define EPS_D 1e-6f

typedef float v2f __attribute__((ext_vector_type(2)));
static __device__ __forceinline__ v2f v2(float a, float b) {
  v2f r; r.x = a; r.y = b; return r;
}
static __device__ __forceinline__ v2f splat(float a) {
  v2f r; r.x = a; r.y = a; return r;
}

// ---- Kernel 1: metric = sym(MLP(points)) + eps*I, rW1 block projections,
//      and zero-init of the G accumulator. (unchanged, R1-proven)
__global__ __launch_bounds__(256) void metric_proj_kernel(
    const float* __restrict__ points,
    const float* __restrict__ mW1, const float* __restrict__ mb1,
    const float* __restrict__ mW2, const float* __restrict__ mb2,
    const float* __restrict__ rW1, const float* __restrict__ rb1,
    float* __restrict__ metric,
    float* __restrict__ A1, float* __restrict__ Mi, float* __restrict__ Mj,
    float* __restrict__ G) {
  int b = blockIdx.x;
  int t = threadIdx.x;  // 0..255
  __shared__ float p[16];
  __shared__ float mh[128];
  __shared__ float raw[256];
  __shared__ float M[256];
  G[b * 256 + t] = 0.f;
  if (t < 16) p[t] = points[b * 16 + t];
  __syncthreads();
  if (t < 128) {
    float acc = mb1[t];
#pragma unroll
    for (int k = 0; k < 16; ++k) acc = fmaf(p[k], mW1[k * 128 + t], acc);
    mh[t] = fmaxf(acc, 0.f);
  }
  __syncthreads();
  {
    float acc = mb2[t];
#pragma unroll 8
    for (int h = 0; h < 128; ++h) acc = fmaf(mh[h], mW2[h * 256 + t], acc);
    raw[t] = acc;
  }
  __syncthreads();
  {
    int i = t >> 4, j = t & 15;
    float v = 0.5f * (raw[i * 16 + j] + raw[j * 16 + i]);
    if (i == j) v += EPS_D;
    M[t] = v;
    metric[b * 256 + t] = v;
  }
  __syncthreads();
  {
    int h = t;
    float wB[16], wC[16];
#pragma unroll
    for (int c = 0; c < 16; ++c) {
      wB[c] = rW1[(16 + c) * 256 + h];
      wC[c] = rW1[(32 + c) * 256 + h];
    }
    float a = rb1[h];
#pragma unroll
    for (int r = 0; r < 16; ++r) a = fmaf(p[r], rW1[r * 256 + h], a);
    A1[b * 256 + h] = a;
#pragma unroll 2
    for (int i = 0; i < 16; ++i) {
      float mi = 0.f, mj = 0.f;
#pragma unroll
      for (int c = 0; c < 16; ++c) {
        float m = M[i * 16 + c];
        mi = fmaf(m, wB[c], mi);
        mj = fmaf(m, wC[c], mj);
      }
      Mi[(b * 16 + i) * 256 + h] = mi;
      Mj[(b * 16 + i) * 256 + h] = mj;
    }
  }
}

// ---- Kernel 2: fused christoffel MLP + ricci layer-1 relu + i-reduction ----
// One 128-thread block (2 waves) per (b,i). R4-proven data flow.
// R8: (1) christoffel weights are read from GLOBAL with loop-uniform
// indices -> compiler emits s_load into SGPRs (hoisted deep, zero VGPR
// cost), deleting the per-iteration ds_read_b128 of z[]/w2p[] that sat on
// the critical path with ~100cyc LDS latency and no VGPR headroom to run
// ahead (VGPR_Count was pinned at 32 for 7 rounds). S = 2*log2(e) is now
// applied inside the exp2 argument (one v_pk_mul per unit).
// (2) amdgpu_waves_per_eu(4,4): max waves = the MEASURED residency (~4/EU,
// stable across (128,6)/(128,8)/256-thr variants), so the allocator stops
// minimizing VGPRs for a phantom 8-wave occupancy.
__attribute__((amdgpu_waves_per_eu(4, 4)))
__global__ __launch_bounds__(128) void chr_kernel(
    const float* __restrict__ metric,
    const float* __restrict__ cW1, const float* __restrict__ cb1,
    const float* __restrict__ cW2, const float* __restrict__ cb2,
    const float* __restrict__ rW1,
    const float* __restrict__ A1, const float* __restrict__ Mi,
    const float* __restrict__ Mj,
    float* __restrict__ G) {
  int bi = blockIdx.x;         // b*16 + i
  int b = bi >> 4, i = bi & 15;
  int t = threadIdx.x;         // 0..127
  int w = t >> 6, l = t & 63;  // wave, lane
  __shared__ float M[256];
  __shared__ float4 ch4[64];   // christoffel tile (256 floats)
  float* chf = (float*)ch4;
  M[t] = metric[b * 256 + t];
  M[t + 128] = metric[b * 256 + t + 128];
  __syncthreads();

  // ---- phase 1: 2 triples per lane: jk0 = 128w + l, jk1 = jk0 + 64 ----
  {
    int jk0 = w * 128 + l, jk1 = jk0 + 64;
    int j0 = jk0 >> 4, k0 = jk0 & 15;
    int j1 = jk1 >> 4, k1 = jk1 & 15;
    v2f x0 = v2(M[i * 16 + j0], M[i * 16 + j1]);
    v2f x1 = v2(M[j0 * 16 + k0], M[j1 * 16 + k1]);
    v2f x2 = v2(M[k0 * 16 + i], M[k1 * 16 + i]);
    v2f acc = splat(cb2[0]);
    const float S = 2.8853900817779268f;  // 2 * log2(e)
    for (int hq = 0; hq < 32; ++hq) {
#pragma unroll
      for (int u = 0; u < 4; ++u) {
        int h = hq * 4 + u;
        // loop-uniform indices -> s_load to SGPRs, no LDS, no VGPR cost
        float q0 = cW1[h];
        float q1 = cW1[128 + h];
        float q2 = cW1[256 + h];
        float qb = cb1[h];
        float w2h = cW2[h];
        v2f pre = __builtin_elementwise_fma(
            x0, splat(q0),
            __builtin_elementwise_fma(
                x1, splat(q1),
                __builtin_elementwise_fma(x2, splat(q2), splat(qb))));
        v2f spre = pre * splat(S);
        v2f e;
        e.x = __builtin_amdgcn_exp2f(spre.x);
        e.y = __builtin_amdgcn_exp2f(spre.y);
        v2f ep = e + splat(1.f);
        v2f r;
        r.x = __builtin_amdgcn_rcpf(ep.x);
        r.y = __builtin_amdgcn_rcpf(ep.y);
        v2f th = __builtin_elementwise_fma(splat(-2.f), r, splat(1.f));
        acc = __builtin_elementwise_fma(th, splat(w2h), acc);
      }
    }
    chf[jk0] = acc.x;
    chf[jk1] = acc.y;
  }
  __syncthreads();

  // ---- phase 2: hidden units h0 = 2t, h1 = 2t+1; float2 global loads ----
  // (byte-identical to R4's proven version)
  {
    int h2 = 2 * t;
    v2f rc2[16];
#pragma unroll
    for (int kk = 0; kk < 16; ++kk) {
      float2 rv = *(const float2*)&rW1[(48 + kk) * 256 + h2];
      rc2[kk] = v2(rv.x, rv.y);
    }
    float2 a1v = *(const float2*)&A1[b * 256 + h2];
    float2 miv = *(const float2*)&Mi[bi * 256 + h2];
    v2f base = v2(a1v.x + miv.x, a1v.y + miv.y);
    v2f hacc = splat(0.f);
    for (int jj = 0; jj < 16; ++jj) {
      float4 c0 = ch4[jj * 4 + 0];
      float4 c1 = ch4[jj * 4 + 1];
      float4 c2v = ch4[jj * 4 + 2];
      float4 c3 = ch4[jj * 4 + 3];
      float2 mjv = *(const float2*)&Mj[(b * 16 + jj) * 256 + h2];
      v2f cp = base + v2(mjv.x, mjv.y);
      float cc[16] = {c0.x, c0.y, c0.z, c0.w, c1.x, c1.y, c1.z, c1.w,
                      c2v.x, c2v.y, c2v.z, c2v.w, c3.x, c3.y, c3.z, c3.w};
#pragma unroll
      for (int kk = 0; kk < 16; ++kk)
        cp = __builtin_elementwise_fma(splat(cc[kk]), rc2[kk], cp);
      v2f rl;
      rl.x = fmaxf(cp.x, 0.f);
      rl.y = fmaxf(cp.y, 0.f);
      hacc += rl;
    }
    atomicAdd(&G[b * 256 + h2], hacc.x);
    atomicAdd(&G[b * 256 + h2 + 1], hacc.y);
  }
}

// ---- Kernel 3: linear layer 2 on G, symmetrize, scale (unchanged) ---------
__global__ __launch_bounds__(256) void final_kernel(
    const float* __restrict__ G,
    const float* __restrict__ rW2, const float* __restrict__ rb2,
    float* __restrict__ out) {
  int b = blockIdx.x;
  int t = threadIdx.x;
  __shared__ float4 Gs[64];
  __shared__ float T[256];
  if (t < 64) Gs[t] = ((const float4*)(G + b * 256))[t];
  __syncthreads();
  float acc = 256.f * rb2[t];
#pragma unroll 4
  for (int h4 = 0; h4 < 64; ++h4) {
    float4 gg = Gs[h4];
    acc = fmaf(gg.x, rW2[(h4 * 4 + 0) * 256 + t], acc);
    acc = fmaf(gg.y, rW2[(h4 * 4 + 1) * 256 + t], acc);
    acc = fmaf(gg.z, rW2[(h4 * 4 + 2) * 256 + t], acc);
    acc = fmaf(gg.w, rW2[(h4 * 4 + 3) * 256 + t], acc);
  }
  T[t] = acc * (1.f / 256.f);
  __syncthreads();
  int k = t >> 4, lcol = t & 15;
  out[b * 256 + t] = 0.5f * (T[k * 16 + lcol] + T[lcol * 16 + k]);
}

extern "C" void kernel_launch(void* const* d_in, const int* in_sizes, int n_in,
                              void* d_out, int out_size, void* d_ws, size_t ws_size,
                              hipStream_t stream) {
  const float* points = (const float*)d_in[0];
  const float* mW1 = (const float*)d_in[1];
  const float* mb1 = (const float*)d_in[2];
  const float* mW2 = (const float*)d_in[3];
  const float* mb2 = (const float*)d_in[4];
  const float* cW1 = (const float*)d_in[5];
  const float* cb1 = (const float*)d_in[6];
  const float* cW2 = (const float*)d_in[7];
  const float* cb2 = (const float*)d_in[8];
  const float* rW1 = (const float*)d_in[9];
  const float* rb1 = (const float*)d_in[10];
  const float* rW2 = (const float*)d_in[11];
  const float* rb2 = (const float*)d_in[12];
  float* out = (float*)d_out;

  float* ws = (float*)d_ws;
  float* metric = ws;                 // 65536
  float* A1 = metric + 65536;         // 65536
  float* Mi = A1 + 65536;             // 1048576
  float* Mj = Mi + 1048576;           // 1048576
  float* G = Mj + 1048576;            // 65536

  metric_proj_kernel<<<BATCH, 256, 0, stream>>>(points, mW1, mb1, mW2, mb2,
                                                rW1, rb1, metric, A1, Mi, Mj, G);
  chr_kernel<<<BATCH * NDIM, 128, 0, stream>>>(metric, cW1, cb1, cW2, cb2, rW1,
                                               A1, Mi, Mj, G);
  final_kernel<<<BATCH, 256, 0, stream>>>(G, rW2, rb2, out);
}

// Round 9
// 140.690 us; speedup vs baseline: 1.0070x; 1.0070x over previous
//
#include <hip/hip_runtime.h>
#include <hip/hip_bf16.h>

#define NDIM 16
#define HDIM 128
#define BATCH 256
#define EPS_D 1e-6f

typedef float v2f __attribute__((ext_vector_type(2)));
static __device__ __forceinline__ v2f v2(float a, float b) {
  v2f r; r.x = a; r.y = b; return r;
}
static __device__ __forceinline__ v2f splat(float a) {
  v2f r; r.x = a; r.y = a; return r;
}

// ---- Kernel 1: metric = sym(MLP(points)) + eps*I, rW1 block projections,
//      and zero-init of the G accumulator. (unchanged, R1-proven)
__global__ __launch_bounds__(256) void metric_proj_kernel(
    const float* __restrict__ points,
    const float* __restrict__ mW1, const float* __restrict__ mb1,
    const float* __restrict__ mW2, const float* __restrict__ mb2,
    const float* __restrict__ rW1, const float* __restrict__ rb1,
    float* __restrict__ metric,
    float* __restrict__ A1, float* __restrict__ Mi, float* __restrict__ Mj,
    float* __restrict__ G) {
  int b = blockIdx.x;
  int t = threadIdx.x;  // 0..255
  __shared__ float p[16];
  __shared__ float mh[128];
  __shared__ float raw[256];
  __shared__ float M[256];
  G[b * 256 + t] = 0.f;
  if (t < 16) p[t] = points[b * 16 + t];
  __syncthreads();
  if (t < 128) {
    float acc = mb1[t];
#pragma unroll
    for (int k = 0; k < 16; ++k) acc = fmaf(p[k], mW1[k * 128 + t], acc);
    mh[t] = fmaxf(acc, 0.f);
  }
  __syncthreads();
  {
    float acc = mb2[t];
#pragma unroll 8
    for (int h = 0; h < 128; ++h) acc = fmaf(mh[h], mW2[h * 256 + t], acc);
    raw[t] = acc;
  }
  __syncthreads();
  {
    int i = t >> 4, j = t & 15;
    float v = 0.5f * (raw[i * 16 + j] + raw[j * 16 + i]);
    if (i == j) v += EPS_D;
    M[t] = v;
    metric[b * 256 + t] = v;
  }
  __syncthreads();
  {
    int h = t;
    float wB[16], wC[16];
#pragma unroll
    for (int c = 0; c < 16; ++c) {
      wB[c] = rW1[(16 + c) * 256 + h];
      wC[c] = rW1[(32 + c) * 256 + h];
    }
    float a = rb1[h];
#pragma unroll
    for (int r = 0; r < 16; ++r) a = fmaf(p[r], rW1[r * 256 + h], a);
    A1[b * 256 + h] = a;
#pragma unroll 2
    for (int i = 0; i < 16; ++i) {
      float mi = 0.f, mj = 0.f;
#pragma unroll
      for (int c = 0; c < 16; ++c) {
        float m = M[i * 16 + c];
        mi = fmaf(m, wB[c], mi);
        mj = fmaf(m, wC[c], mj);
      }
      Mi[(b * 16 + i) * 256 + h] = mi;
      Mj[(b * 16 + i) * 256 + h] = mj;
    }
  }
}

// ---- Kernel 2: fused christoffel MLP + ricci layer-1 relu + i-reduction ----
// R9: block = (b, i-pair), 128 threads, grid 2048. Wave w runs phase 1 for
// i = 2*ip + w with FOUR triples per lane as TWO independent v2f chains
// (A: jk=l,l+64; B: jk=l+128,l+192). The chains have disjoint inputs and
// outputs, so their liveness (~16 VGPR) is irreducible - the compiler
// cannot collapse them the way it undid R7's same-chain pass-splitting.
// Their exp/rcp dependency chains interleave -> per-wave stall halves.
// Phase 2 handles both i's per thread, SHARING rc2[] and Mj loads (global
// traffic and G-atomics halved) - two more independent fma chains.
// Weights staged in LDS exactly as the proven R4 kernel (R8's s_load
// variant serialized on lgkmcnt; reverted).
__global__ __launch_bounds__(128, 4) void chr_kernel(
    const float* __restrict__ metric,
    const float* __restrict__ cW1, const float* __restrict__ cb1,
    const float* __restrict__ cW2, const float* __restrict__ cb2,
    const float* __restrict__ rW1,
    const float* __restrict__ A1, const float* __restrict__ Mi,
    const float* __restrict__ Mj,
    float* __restrict__ G) {
  int blk = blockIdx.x;        // b*8 + ip
  int b = blk >> 3, ip = blk & 7;
  int t = threadIdx.x;         // 0..127
  int w = t >> 6, l = t & 63;  // wave, lane
  int i = ip * 2 + w;          // this wave's i for phase 1
  __shared__ float M[256];
  __shared__ float4 z[128];      // {S*w1_0h, S*w1_1h, S*w1_2h, S*b1h}
  __shared__ float4 w2p[32];     // cW2 packed 4-wide
  __shared__ float4 ch4[2][64];  // per-i christoffel tile (256 floats each)
  M[t] = metric[b * 256 + t];
  M[t + 128] = metric[b * 256 + t + 128];
  {
    const float S = 2.8853900817779268f;  // 2 * log2(e)
    z[t] = make_float4(S * cW1[t], S * cW1[128 + t], S * cW1[256 + t],
                       S * cb1[t]);
    ((float*)w2p)[t] = cW2[t];
  }
  __syncthreads();

  // ---- phase 1: 4 triples per lane, two independent v2f chains ----
  {
    float* chf = (float*)ch4[w];
    int jA0 = l >> 4, kA0 = l & 15;
    int jA1 = (l + 64) >> 4, kA1 = (l + 64) & 15;
    int jB0 = (l + 128) >> 4, kB0 = (l + 128) & 15;
    int jB1 = (l + 192) >> 4, kB1 = (l + 192) & 15;
    v2f x0A = v2(M[i * 16 + jA0], M[i * 16 + jA1]);
    v2f x1A = v2(M[jA0 * 16 + kA0], M[jA1 * 16 + kA1]);
    v2f x2A = v2(M[kA0 * 16 + i], M[kA1 * 16 + i]);
    v2f x0B = v2(M[i * 16 + jB0], M[i * 16 + jB1]);
    v2f x1B = v2(M[jB0 * 16 + kB0], M[jB1 * 16 + kB1]);
    v2f x2B = v2(M[kB0 * 16 + i], M[kB1 * 16 + i]);
    v2f accA = splat(cb2[0]);
    v2f accB = splat(cb2[0]);
    for (int hq = 0; hq < 32; ++hq) {
      float4 W2 = w2p[hq];
      float w2u[4] = {W2.x, W2.y, W2.z, W2.w};
#pragma unroll
      for (int u = 0; u < 4; ++u) {
        float4 Q = z[hq * 4 + u];
        v2f preA = __builtin_elementwise_fma(
            x0A, splat(Q.x),
            __builtin_elementwise_fma(
                x1A, splat(Q.y),
                __builtin_elementwise_fma(x2A, splat(Q.z), splat(Q.w))));
        v2f preB = __builtin_elementwise_fma(
            x0B, splat(Q.x),
            __builtin_elementwise_fma(
                x1B, splat(Q.y),
                __builtin_elementwise_fma(x2B, splat(Q.z), splat(Q.w))));
        v2f eA, eB;
        eA.x = __builtin_amdgcn_exp2f(preA.x);
        eA.y = __builtin_amdgcn_exp2f(preA.y);
        eB.x = __builtin_amdgcn_exp2f(preB.x);
        eB.y = __builtin_amdgcn_exp2f(preB.y);
        v2f epA = eA + splat(1.f);
        v2f epB = eB + splat(1.f);
        v2f rA, rB;
        rA.x = __builtin_amdgcn_rcpf(epA.x);
        rA.y = __builtin_amdgcn_rcpf(epA.y);
        rB.x = __builtin_amdgcn_rcpf(epB.x);
        rB.y = __builtin_amdgcn_rcpf(epB.y);
        v2f thA = __builtin_elementwise_fma(splat(-2.f), rA, splat(1.f));
        v2f thB = __builtin_elementwise_fma(splat(-2.f), rB, splat(1.f));
        accA = __builtin_elementwise_fma(thA, splat(w2u[u]), accA);
        accB = __builtin_elementwise_fma(thB, splat(w2u[u]), accB);
      }
    }
    chf[l] = accA.x;
    chf[l + 64] = accA.y;
    chf[l + 128] = accB.x;
    chf[l + 192] = accB.y;
  }
  __syncthreads();

  // ---- phase 2: h0 = 2t, h1 = 2t+1 for BOTH i's; shared rc2/Mj loads ----
  {
    int h2 = 2 * t;
    int bi0 = b * 16 + ip * 2, bi1 = bi0 + 1;
    v2f rc2[16];
#pragma unroll
    for (int kk = 0; kk < 16; ++kk) {
      float2 rv = *(const float2*)&rW1[(48 + kk) * 256 + h2];
      rc2[kk] = v2(rv.x, rv.y);
    }
    float2 a1v = *(const float2*)&A1[b * 256 + h2];
    float2 mi0 = *(const float2*)&Mi[bi0 * 256 + h2];
    float2 mi1 = *(const float2*)&Mi[bi1 * 256 + h2];
    v2f base0 = v2(a1v.x + mi0.x, a1v.y + mi0.y);
    v2f base1 = v2(a1v.x + mi1.x, a1v.y + mi1.y);
    v2f hacc0 = splat(0.f);
    v2f hacc1 = splat(0.f);
    for (int jj = 0; jj < 16; ++jj) {
      float2 mjv = *(const float2*)&Mj[(b * 16 + jj) * 256 + h2];
      v2f mj2 = v2(mjv.x, mjv.y);
      float4 c0 = ch4[0][jj * 4 + 0];
      float4 c1 = ch4[0][jj * 4 + 1];
      float4 c2v = ch4[0][jj * 4 + 2];
      float4 c3 = ch4[0][jj * 4 + 3];
      float4 d0 = ch4[1][jj * 4 + 0];
      float4 d1 = ch4[1][jj * 4 + 1];
      float4 d2v = ch4[1][jj * 4 + 2];
      float4 d3 = ch4[1][jj * 4 + 3];
      v2f cp0 = base0 + mj2;
      v2f cp1 = base1 + mj2;
      float cc0[16] = {c0.x, c0.y, c0.z, c0.w, c1.x, c1.y, c1.z, c1.w,
                       c2v.x, c2v.y, c2v.z, c2v.w, c3.x, c3.y, c3.z, c3.w};
      float cc1[16] = {d0.x, d0.y, d0.z, d0.w, d1.x, d1.y, d1.z, d1.w,
                       d2v.x, d2v.y, d2v.z, d2v.w, d3.x, d3.y, d3.z, d3.w};
#pragma unroll
      for (int kk = 0; kk < 16; ++kk) {
        cp0 = __builtin_elementwise_fma(splat(cc0[kk]), rc2[kk], cp0);
        cp1 = __builtin_elementwise_fma(splat(cc1[kk]), rc2[kk], cp1);
      }
      v2f rl0, rl1;
      rl0.x = fmaxf(cp0.x, 0.f);
      rl0.y = fmaxf(cp0.y, 0.f);
      rl1.x = fmaxf(cp1.x, 0.f);
      rl1.y = fmaxf(cp1.y, 0.f);
      hacc0 += rl0;
      hacc1 += rl1;
    }
    atomicAdd(&G[b * 256 + h2], hacc0.x + hacc1.x);
    atomicAdd(&G[b * 256 + h2 + 1], hacc0.y + hacc1.y);
  }
}

// ---- Kernel 3: linear layer 2 on G, symmetrize, scale (unchanged) ---------
__global__ __launch_bounds__(256) void final_kernel(
    const float* __restrict__ G,
    const float* __restrict__ rW2, const float* __restrict__ rb2,
    float* __restrict__ out) {
  int b = blockIdx.x;
  int t = threadIdx.x;
  __shared__ float4 Gs[64];
  __shared__ float T[256];
  if (t < 64) Gs[t] = ((const float4*)(G + b * 256))[t];
  __syncthreads();
  float acc = 256.f * rb2[t];
#pragma unroll 4
  for (int h4 = 0; h4 < 64; ++h4) {
    float4 gg = Gs[h4];
    acc = fmaf(gg.x, rW2[(h4 * 4 + 0) * 256 + t], acc);
    acc = fmaf(gg.y, rW2[(h4 * 4 + 1) * 256 + t], acc);
    acc = fmaf(gg.z, rW2[(h4 * 4 + 2) * 256 + t], acc);
    acc = fmaf(gg.w, rW2[(h4 * 4 + 3) * 256 + t], acc);
  }
  T[t] = acc * (1.f / 256.f);
  __syncthreads();
  int k = t >> 4, lcol = t & 15;
  out[b * 256 + t] = 0.5f * (T[k * 16 + lcol] + T[lcol * 16 + k]);
}

extern "C" void kernel_launch(void* const* d_in, const int* in_sizes, int n_in,
                              void* d_out, int out_size, void* d_ws, size_t ws_size,
                              hipStream_t stream) {
  const float* points = (const float*)d_in[0];
  const float* mW1 = (const float*)d_in[1];
  const float* mb1 = (const float*)d_in[2];
  const float* mW2 = (const float*)d_in[3];
  const float* mb2 = (const float*)d_in[4];
  const float* cW1 = (const float*)d_in[5];
  const float* cb1 = (const float*)d_in[6];
  const float* cW2 = (const float*)d_in[7];
  const float* cb2 = (const float*)d_in[8];
  const float* rW1 = (const float*)d_in[9];
  const float* rb1 = (const float*)d_in[10];
  const float* rW2 = (const float*)d_in[11];
  const float* rb2 = (const float*)d_in[12];
  float* out = (float*)d_out;

  float* ws = (float*)d_ws;
  float* metric = ws;                 // 65536
  float* A1 = metric + 65536;         // 65536
  float* Mi = A1 + 65536;             // 1048576
  float* Mj = Mi + 1048576;           // 1048576
  float* G = Mj + 1048576;            // 65536

  metric_proj_kernel<<<BATCH, 256, 0, stream>>>(points, mW1, mb1, mW2, mb2,
                                                rW1, rb1, metric, A1, Mi, Mj, G);
  chr_kernel<<<BATCH * 8, 128, 0, stream>>>(metric, cW1, cb1, cW2, cb2, rW1,
                                            A1, Mi, Mj, G);
  final_kernel<<<BATCH, 256, 0, stream>>>(G, rW2, rb2, out);
}